// Round 3
// baseline (271.955 us; speedup 1.0000x reference)
//
#include <hip/hip_runtime.h>

#define NUM_BINS 128
#define BATCH 128
#define HW (512 * 512)            // elements per image
#define BLOCKS_PER_IMG 32
#define ELEMS_PER_BLOCK (HW / BLOCKS_PER_IMG)   // 8192
#define HIST_THREADS 256
#define NCOPY 32                  // one histogram copy per LDS bank
#define SLICES_PER_IMG 16
#define SLICE (HW / SLICES_PER_IMG)             // 16384 floats per slice

// ---------------------------------------------------------------------------
// Kernel 1: per-tile histogram, torch.histc(min=0,max=1) semantics.
// 32 bank-interleaved histogram copies (zero intra-wave LDS conflicts).
// Each tile's 128-bin partial is written 16x: one copy into each of its
// image's 16 scale-slices, staged in the OUTPUT buffer. No workspace,
// no global atomics, no memset.
// ---------------------------------------------------------------------------
__global__ __launch_bounds__(HIST_THREADS) void hist_kernel(
    const float* __restrict__ x, unsigned int* __restrict__ outu) {
    __shared__ unsigned int lhist[NUM_BINS * NCOPY];   // 16 KiB, [bin][copy]

    const int tid = threadIdx.x;
    const int cpy = tid & 31;

    for (int i = tid; i < NUM_BINS * NCOPY; i += HIST_THREADS)
        lhist[i] = 0u;
    __syncthreads();

    const int b   = blockIdx.x / BLOCKS_PER_IMG;
    const int blk = blockIdx.x % BLOCKS_PER_IMG;
    const float4* xp =
        (const float4*)(x + (size_t)b * HW + (size_t)blk * ELEMS_PER_BLOCK);
    const int n4 = ELEMS_PER_BLOCK / 4;   // 2048 float4 per tile

    for (int i = tid; i < n4; i += HIST_THREADS) {
        float4 v = xp[i];
        float vals[4] = {v.x, v.y, v.z, v.w};
#pragma unroll
        for (int k = 0; k < 4; ++k) {
            float f = vals[k];
            if (f >= 0.0f && f <= 1.0f) {
                int idx = (int)(f * (float)NUM_BINS);  // trunc == floor (f>=0)
                idx = min(idx, NUM_BINS - 1);          // f==1.0 -> last bin
                atomicAdd(&lhist[idx * NCOPY + cpy], 1u);
            }
        }
    }
    __syncthreads();

    // Reduce the 32 copies (rotated, conflict-free) and replicate the partial
    // into all 16 slice-stashes of this image.
    if (tid < NUM_BINS) {
        unsigned int s = 0u;
#pragma unroll
        for (int c = 0; c < NCOPY; ++c)
            s += lhist[tid * NCOPY + ((c + tid) & 31)];
        unsigned int* base = outu + (size_t)b * HW + (size_t)blk * NUM_BINS;
#pragma unroll
        for (int j = 0; j < SLICES_PER_IMG; ++j)
            base[(size_t)j * SLICE + tid] = s;
    }
}

// ---------------------------------------------------------------------------
// Kernel 2: fused MLP + scale. One block per (image, slice).
// Each block reads ONLY its own slice's stash (written by K1, visible via
// kernel boundary), sums the 32 partials, redundantly computes
// w = relu(hist @ W1 + b1) @ W2 + b2, then scales its 64 KB slice of x —
// overwriting its own stash only after __syncthreads(). No cross-block
// read/write hazard exists by construction; output depends only on x, so
// repeated graph replays are idempotent.
// ---------------------------------------------------------------------------
__global__ __launch_bounds__(256) void mlp_scale_kernel(
    const float* __restrict__ x,
    const float* __restrict__ W1, const float* __restrict__ b1,
    const float* __restrict__ W2, const float* __restrict__ b2,
    float* __restrict__ out) {
    __shared__ float shist[NUM_BINS];
    __shared__ float hred[16];
    __shared__ float wsh;

    const int b = blockIdx.x / SLICES_PER_IMG;
    const int j = blockIdx.x % SLICES_PER_IMG;
    const int t = threadIdx.x;

    const unsigned int* stash =
        (const unsigned int*)out + (size_t)b * HW + (size_t)j * SLICE;

    if (t < NUM_BINS) {
        unsigned int s = 0u;
#pragma unroll
        for (int blk = 0; blk < BLOCKS_PER_IMG; ++blk)
            s += stash[blk * NUM_BINS + t];
        shist[t] = (float)s;
    }
    __syncthreads();

    if (t < 16) {
        float acc = b1[t];
#pragma unroll 8
        for (int k = 0; k < NUM_BINS; ++k)
            acc = fmaf(shist[k], W1[k * 16 + t], acc);
        hred[t] = fmaxf(acc, 0.0f) * W2[t];   // W2 is [16,1]
    }
    __syncthreads();

    if (t == 0) {
        float s = b2[0];
#pragma unroll
        for (int i = 0; i < 16; ++i) s += hred[i];
        wsh = s;
    }
    __syncthreads();

    const float w = wsh;
    const float4* xp = (const float4*)(x + (size_t)b * HW + (size_t)j * SLICE);
    float4* op = (float4*)(out + (size_t)b * HW + (size_t)j * SLICE);
#pragma unroll 4
    for (int i = t; i < SLICE / 4; i += 256) {
        float4 v = xp[i];
        v.x *= w; v.y *= w; v.z *= w; v.w *= w;
        op[i] = v;
    }
}

extern "C" void kernel_launch(void* const* d_in, const int* in_sizes, int n_in,
                              void* d_out, int out_size, void* d_ws, size_t ws_size,
                              hipStream_t stream) {
    const float* x  = (const float*)d_in[0];
    const float* W1 = (const float*)d_in[1];
    const float* b1 = (const float*)d_in[2];
    const float* W2 = (const float*)d_in[3];
    const float* b2 = (const float*)d_in[4];
    float* out = (float*)d_out;

    // No workspace use: partial histograms are staged inside the output
    // buffer (replicated per slice) and overwritten by the final scale.
    (void)d_ws; (void)ws_size;

    hist_kernel<<<BATCH * BLOCKS_PER_IMG, HIST_THREADS, 0, stream>>>(
        x, (unsigned int*)out);
    mlp_scale_kernel<<<BATCH * SLICES_PER_IMG, 256, 0, stream>>>(
        x, W1, b1, W2, b2, out);
}

// Round 4
// 266.099 us; speedup vs baseline: 1.0220x; 1.0220x over previous
//
#include <hip/hip_runtime.h>

#define NUM_BINS 128
#define BATCH 128
#define HW (512 * 512)            // elements per image
#define BLOCKS_PER_IMG 32
#define ELEMS_PER_BLOCK (HW / BLOCKS_PER_IMG)   // 8192
#define HIST_THREADS 256
#define NCOPY 32                  // one histogram copy per LDS bank
#define SLICES_PER_IMG 16
#define SLICE (HW / SLICES_PER_IMG)             // 16384 floats per slice

// ---------------------------------------------------------------------------
// Kernel 1: per-tile histogram, torch.histc(min=0,max=1) semantics.
// 32 bank-interleaved histogram copies: lane l atomics into copy (l&31) at
// bin*32+(l&31) -> bank == l&31 always -> zero intra-wave bank conflicts.
// Writes one 512 B partial per tile into the workspace (no memset needed:
// every bin of every partial is written unconditionally).
// ---------------------------------------------------------------------------
__global__ __launch_bounds__(HIST_THREADS) void hist_kernel(
    const float* __restrict__ x, unsigned int* __restrict__ part) {
    __shared__ unsigned int lhist[NUM_BINS * NCOPY];   // 16 KiB, [bin][copy]

    const int tid = threadIdx.x;
    const int cpy = tid & 31;

    for (int i = tid; i < NUM_BINS * NCOPY; i += HIST_THREADS)
        lhist[i] = 0u;
    __syncthreads();

    const int b   = blockIdx.x / BLOCKS_PER_IMG;
    const int blk = blockIdx.x % BLOCKS_PER_IMG;
    const float4* xp =
        (const float4*)(x + (size_t)b * HW + (size_t)blk * ELEMS_PER_BLOCK);
    const int n4 = ELEMS_PER_BLOCK / 4;   // 2048 float4 per tile

    for (int i = tid; i < n4; i += HIST_THREADS) {
        float4 v = xp[i];
        float vals[4] = {v.x, v.y, v.z, v.w};
#pragma unroll
        for (int k = 0; k < 4; ++k) {
            float f = vals[k];
            if (f >= 0.0f && f <= 1.0f) {
                int idx = (int)(f * (float)NUM_BINS);  // trunc == floor (f>=0)
                idx = min(idx, NUM_BINS - 1);          // f==1.0 -> last bin
                atomicAdd(&lhist[idx * NCOPY + cpy], 1u);
            }
        }
    }
    __syncthreads();

    // Reduce the 32 copies per bin (rotated start -> conflict-free reads).
    if (tid < NUM_BINS) {
        unsigned int s = 0u;
#pragma unroll
        for (int c = 0; c < NCOPY; ++c)
            s += lhist[tid * NCOPY + ((c + tid) & 31)];
        part[((size_t)b * BLOCKS_PER_IMG + blk) * NUM_BINS + tid] = s;
    }
}

// ---------------------------------------------------------------------------
// Kernel 2: fused MLP + scale. One block per (image, slice); 2048 blocks.
// Each block redundantly reduces its image's 32 partials (16 KB, L3-hot),
// computes w = relu(hist @ W1 + b1) @ W2 + b2 in-block, then streams its
// 64 KB slice: out = x * w. x is L3-warm from K1's read (134 MB < 256 MB L3).
// ---------------------------------------------------------------------------
__global__ __launch_bounds__(256) void mlp_scale_kernel(
    const float* __restrict__ x,
    const unsigned int* __restrict__ part,
    const float* __restrict__ W1, const float* __restrict__ b1,
    const float* __restrict__ W2, const float* __restrict__ b2,
    float* __restrict__ out) {
    __shared__ float shist[NUM_BINS];
    __shared__ float hred[16];
    __shared__ float wsh;

    const int b = blockIdx.x / SLICES_PER_IMG;
    const int j = blockIdx.x % SLICES_PER_IMG;
    const int t = threadIdx.x;

    if (t < NUM_BINS) {
        const unsigned int* p = part + (size_t)b * BLOCKS_PER_IMG * NUM_BINS + t;
        unsigned int s = 0u;
#pragma unroll
        for (int blk = 0; blk < BLOCKS_PER_IMG; ++blk)
            s += p[blk * NUM_BINS];
        shist[t] = (float)s;
    }
    __syncthreads();

    if (t < 16) {
        float acc = b1[t];
#pragma unroll 8
        for (int k = 0; k < NUM_BINS; ++k)
            acc = fmaf(shist[k], W1[k * 16 + t], acc);
        hred[t] = fmaxf(acc, 0.0f) * W2[t];   // W2 is [16,1]
    }
    __syncthreads();

    if (t == 0) {
        float s = b2[0];
#pragma unroll
        for (int i = 0; i < 16; ++i) s += hred[i];
        wsh = s;
    }
    __syncthreads();

    const float w = wsh;
    const float4* xp = (const float4*)(x + (size_t)b * HW + (size_t)j * SLICE);
    float4* op = (float4*)(out + (size_t)b * HW + (size_t)j * SLICE);
#pragma unroll 4
    for (int i = t; i < SLICE / 4; i += 256) {
        float4 v = xp[i];
        v.x *= w; v.y *= w; v.z *= w; v.w *= w;
        op[i] = v;
    }
}

extern "C" void kernel_launch(void* const* d_in, const int* in_sizes, int n_in,
                              void* d_out, int out_size, void* d_ws, size_t ws_size,
                              hipStream_t stream) {
    const float* x  = (const float*)d_in[0];
    const float* W1 = (const float*)d_in[1];
    const float* b1 = (const float*)d_in[2];
    const float* W2 = (const float*)d_in[3];
    const float* b2 = (const float*)d_in[4];
    float* out = (float*)d_out;

    // 2 MiB of per-tile partial histograms in the workspace. The harness
    // poisons ws unconditionally (established round 3), so using it is free.
    // Every partial bin is written unconditionally by K1 -> no memset needed.
    unsigned int* part = (unsigned int*)d_ws;

    hist_kernel<<<BATCH * BLOCKS_PER_IMG, HIST_THREADS, 0, stream>>>(x, part);
    mlp_scale_kernel<<<BATCH * SLICES_PER_IMG, 256, 0, stream>>>(
        x, part, W1, b1, W2, b2, out);
}